// Round 7
// baseline (112.020 us; speedup 1.0000x reference)
//
#include <hip/hip_runtime.h>
#include <hip/hip_bf16.h>
#include <stdint.h>

#define NN    4096
#define INF_  256
#define HEADS 4
#define HID   64
#define OUTC  256
#define NEG   0.2f
#define L2E   1.44269504f

#define BI     32
#define JSPLIT 8
#define NJ     (NN / JSPLIT)

typedef short bf16x8 __attribute__((ext_vector_type(8)));
typedef float f32x4  __attribute__((ext_vector_type(4)));

// ---- float <-> order-preserving uint encoding (for atomicMax on f32) ----
__device__ __forceinline__ uint32_t ford(float x){
  uint32_t u = __float_as_uint(x);
  return (u & 0x80000000u) ? ~u : (u | 0x80000000u);
}
__device__ __forceinline__ float funord(uint32_t e){
  uint32_t u = (e & 0x80000000u) ? (e & 0x7fffffffu) : ~e;
  return __uint_as_float(u);
}
__device__ __forceinline__ ushort bf16u(float f){
  __hip_bfloat16 b = __float2bfloat16(f);
  return *reinterpret_cast<ushort*>(&b);
}

// split 8 f32 -> bf16 hi (trunc) + bf16 lo (exact residual, trunc)
__device__ __forceinline__ void split8(float4 a0, float4 a1, bf16x8& hi, bf16x8& lo){
  float av[8] = {a0.x, a0.y, a0.z, a0.w, a1.x, a1.y, a1.z, a1.w};
  ushort hu[8], lu[8];
  #pragma unroll
  for (int q = 0; q < 8; q++){
    uint32_t u = __float_as_uint(av[q]);
    hu[q] = (ushort)(u >> 16);
    float hf = __uint_as_float(u & 0xffff0000u);
    lu[q] = (ushort)(__float_as_uint(av[q] - hf) >> 16);
  }
  hi = *(bf16x8*)hu;
  lo = *(bf16x8*)lu;
}

// ---- fused prep: adjacency->bitmask pack (4/5 of blocks) + g-GEMM (1/5) ----
// interleaved 4:1 so the HBM-bound pack overlaps the latency-bound GEMM.
__launch_bounds__(256)
__global__ void k_prep(const int* __restrict__ adj, const float* __restrict__ hmat,
                       const float* __restrict__ W, const float* __restrict__ aw,
                       uint32_t* __restrict__ bm, short* __restrict__ gT,
                       float* __restrict__ slT2, float* __restrict__ srT2,
                       uint32_t* __restrict__ srmax2){
  __shared__ float red[64][69];   // gemm: [lane][wave*17 + val]; pack reuses as ushort buf
  int bx = blockIdx.x, t = threadIdx.x;
  int role = bx % 5;

  if (role < 4){
    // ---- pack: one adjacency row -> 128 bitmask words ----
    int i = (bx/5)*4 + role;
    ushort* sh = (ushort*)red;
    const int* row = adj + (size_t)i*NN + t*16;
    uint32_t b = 0;
    #pragma unroll
    for (int u = 0; u < 4; u++){
      int4 v = *(const int4*)(row + u*4);
      b |= (v.x ? 1u : 0u) << (u*4 + 0);
      b |= (v.y ? 1u : 0u) << (u*4 + 1);
      b |= (v.z ? 1u : 0u) << (u*4 + 2);
      b |= (v.w ? 1u : 0u) << (u*4 + 3);
    }
    sh[t] = (ushort)b;
    __syncthreads();
    if (t < 128)
      bm[(size_t)i*128 + t] = (uint32_t)sh[2*t] | ((uint32_t)sh[2*t + 1] << 16);
    return;
  }

  // ---- gemm: one (i-tile of 16, head); K split across 4 waves ----
  int id = bx/5;
  int i0 = (id & 255) * 16;
  int hd = id >> 8;
  int w = t >> 6, l = t & 63, lr = l & 15, lg = l >> 4;

  f32x4 acc[4] = {};
  #pragma unroll
  for (int ks = 0; ks < 2; ks++){
    int k0 = w*64 + ks*32 + lg*8;
    const float* ap_ = hmat + (size_t)(i0 + lr)*INF_ + k0;
    float4 a0 = *(const float4*)ap_;
    float4 a1 = *(const float4*)(ap_ + 4);
    bf16x8 ahi, alo;
    split8(a0, a1, ahi, alo);
    #pragma unroll
    for (int n = 0; n < 4; n++){
      const float* wp_ = W + (size_t)(hd*HID + n*16 + lr)*INF_ + k0;
      float4 b0 = *(const float4*)wp_;
      float4 b1 = *(const float4*)(wp_ + 4);
      bf16x8 bhi, blo;
      split8(b0, b1, bhi, blo);
      acc[n] = __builtin_amdgcn_mfma_f32_16x16x32_bf16(ahi, bhi, acc[n], 0, 0, 0);
      acc[n] = __builtin_amdgcn_mfma_f32_16x16x32_bf16(ahi, blo, acc[n], 0, 0, 0);
      acc[n] = __builtin_amdgcn_mfma_f32_16x16x32_bf16(alo, bhi, acc[n], 0, 0, 0);
    }
  }

  // cross-wave K reduce via LDS
  #pragma unroll
  for (int n = 0; n < 4; n++)
    #pragma unroll
    for (int r = 0; r < 4; r++)
      red[l][w*17 + n*4 + r] = acc[n][r];
  __syncthreads();

  if (w == 0){
    #pragma unroll
    for (int ww = 1; ww < 4; ww++)
      #pragma unroll
      for (int n = 0; n < 4; n++)
        #pragma unroll
        for (int r = 0; r < 4; r++)
          acc[n][r] += red[l][ww*17 + n*4 + r];

    // scores (log2e-scaled)
    float alv[4], arv[4];
    #pragma unroll
    for (int n = 0; n < 4; n++){ alv[n] = aw[n*16 + lr]; arv[n] = aw[64 + n*16 + lr]; }
    float rmax = -3.4e38f;
    #pragma unroll
    for (int r = 0; r < 4; r++){
      float slp = 0.f, srp = 0.f;
      #pragma unroll
      for (int n = 0; n < 4; n++){
        slp = fmaf(acc[n][r], alv[n], slp);
        srp = fmaf(acc[n][r], arv[n], srp);
      }
      #pragma unroll
      for (int m = 1; m < 16; m <<= 1){
        slp += __shfl_xor(slp, m, 64);
        srp += __shfl_xor(srp, m, 64);
      }
      slp *= L2E; srp *= L2E;
      if (lr == 0){
        slT2[(size_t)hd*NN + i0 + lg*4 + r] = slp;
        srT2[(size_t)hd*NN + i0 + lg*4 + r] = srp;
      }
      rmax = fmaxf(rmax, srp);
    }
    rmax = fmaxf(rmax, __shfl_xor(rmax, 16, 64));
    rmax = fmaxf(rmax, __shfl_xor(rmax, 32, 64));
    if (l == 0) atomicMax(srmax2 + hd, ford(rmax));

    // gT store: rows lg*4..+4 are consecutive -> uint2 per n, no LDS transpose
    #pragma unroll
    for (int n = 0; n < 4; n++){
      uint32_t p0 = (uint32_t)bf16u(acc[n][0]) | ((uint32_t)bf16u(acc[n][1]) << 16);
      uint32_t p1 = (uint32_t)bf16u(acc[n][2]) | ((uint32_t)bf16u(acc[n][3]) << 16);
      *(uint2*)&gT[(size_t)(hd*HID + n*16 + lr)*NN + i0 + lg*4] = make_uint2(p0, p1);
    }
  }
}

// ---- fused masked-softmax attention: 8 waves (4 heads x 2 i-halves),
//      zero LDS, zero barriers, weights built in MFMA A-frag layout ----
__launch_bounds__(512, 8)
__global__ void k_attn(const short* __restrict__ gT, const float* __restrict__ slT2,
                       const float* __restrict__ srT2, const uint32_t* __restrict__ srmax2,
                       const uint32_t* __restrict__ bm,
                       __hip_bfloat16* __restrict__ num_p, float* __restrict__ den_p){
  int t  = threadIdx.x;
  int w  = t >> 6;
  int h  = w & 3, ihalf = w >> 2;
  int l  = t & 63, lr = l & 15, lg = l >> 4;
  int i0 = blockIdx.x * BI + ihalf * 16;
  int jb = blockIdx.y * NJ;
  int js = blockIdx.y;

  float srmaxh = funord(srmax2[h]);
  float slv = slT2[(size_t)h*NN + i0 + lr];
  float xx  = slv + srmaxh;
  float msh = fmaxf(xx, NEG * xx);
  float d1  = slv - msh;             // z = d1 + sr
  float cc  = (NEG - 1.0f) * msh;    // NEG*z + cc = lrelu-neg branch - msh

  f32x4 acc[4] = {};
  float denp = 0.f;
  const float*    srh = srT2 + (size_t)h*NN + jb;
  const short*    gTh = gT + (size_t)h*HID*NN;
  const uint32_t* bmp = bm + (size_t)(i0 + lr)*128 + (jb >> 5);

  #pragma unroll
  for (int s = 0; s < 16; s++){
    uint32_t word = bmp[s] >> (lg*8);
    int kk = jb + s*32 + lg*8;
    float4 s0 = *(const float4*)(srh + s*32 + lg*8);
    float4 s1 = *(const float4*)(srh + s*32 + lg*8 + 4);
    float sr8[8] = {s0.x, s0.y, s0.z, s0.w, s1.x, s1.y, s1.z, s1.w};

    uint32_t pk[4];
    #pragma unroll
    for (int p = 0; p < 4; p++){
      float z0 = d1 + sr8[2*p];
      float z1 = d1 + sr8[2*p + 1];
      float w0 = __builtin_amdgcn_exp2f(fmaxf(z0, fmaf(NEG, z0, cc)));
      float w1 = __builtin_amdgcn_exp2f(fmaxf(z1, fmaf(NEG, z1, cc)));
      w0 = (word & (1u << (2*p)))     ? w0 : 0.f;
      w1 = (word & (1u << (2*p + 1))) ? w1 : 0.f;
      denp += w0;
      denp += w1;
      pk[p] = ((__float_as_uint(w0) + 0x8000u) >> 16) |
              ((__float_as_uint(w1) + 0x8000u) & 0xffff0000u);
    }
    bf16x8 A = *(bf16x8*)pk;

    bf16x8 B0 = *(const bf16x8*)(gTh + (size_t)(0*16 + lr)*NN + kk);
    bf16x8 B1 = *(const bf16x8*)(gTh + (size_t)(1*16 + lr)*NN + kk);
    acc[0] = __builtin_amdgcn_mfma_f32_16x16x32_bf16(A, B0, acc[0], 0, 0, 0);
    acc[1] = __builtin_amdgcn_mfma_f32_16x16x32_bf16(A, B1, acc[1], 0, 0, 0);
    bf16x8 B2 = *(const bf16x8*)(gTh + (size_t)(2*16 + lr)*NN + kk);
    bf16x8 B3 = *(const bf16x8*)(gTh + (size_t)(3*16 + lr)*NN + kk);
    acc[2] = __builtin_amdgcn_mfma_f32_16x16x32_bf16(A, B2, acc[2], 0, 0, 0);
    acc[3] = __builtin_amdgcn_mfma_f32_16x16x32_bf16(A, B3, acc[3], 0, 0, 0);
  }

  // num partials (bf16): row = i0+lg*4+r, col = h*64+n*16+lr
  #pragma unroll
  for (int n = 0; n < 4; n++)
    #pragma unroll
    for (int r = 0; r < 4; r++)
      num_p[((size_t)js*NN + i0 + lg*4 + r)*OUTC + h*HID + n*16 + lr] =
          __float2bfloat16(acc[n][r]);

  denp += __shfl_xor(denp, 16, 64);
  denp += __shfl_xor(denp, 32, 64);
  if (lg == 0)
    den_p[((size_t)js*4 + h)*NN + i0 + lr] = denp;
}

// ---- combine partials: out = sum(num)/sum(den) ----
__global__ void k_comb(const __hip_bfloat16* __restrict__ num_p,
                       const float* __restrict__ den_p, float* __restrict__ out){
  int r = blockIdx.x, c = threadIdx.x;
  int h = c >> 6;
  float s = 0.f, d = 0.f;
  #pragma unroll
  for (int js = 0; js < JSPLIT; js++)
    s += __bfloat162float(num_p[((size_t)js*NN + r)*OUTC + c]);
  #pragma unroll
  for (int js = 0; js < JSPLIT; js++)
    d += den_p[((size_t)js*4 + h)*NN + r];
  out[(size_t)r*OUTC + c] = s / d;
}

extern "C" void kernel_launch(void* const* d_in, const int* in_sizes, int n_in,
                              void* d_out, int out_size, void* d_ws, size_t ws_size,
                              hipStream_t stream){
  const float* hmat = (const float*)d_in[0];
  const int*   adj  = (const int*)d_in[1];     // int32 layout confirmed in r1
  const float* W    = (const float*)d_in[2];
  const float* aw   = (const float*)d_in[3];
  float* out = (float*)d_out;
  char*  ws  = (char*)d_ws;

  // ws layout (bytes), total ~21.6 MB
  uint32_t* srmax2 = (uint32_t*)(ws);                      // 64 B
  float*    slT2   = (float*)(ws + 1024);                  // 64 KB
  float*    srT2   = (float*)(ws + 66560);                 // 64 KB
  short*    gT     = (short*)(ws + 132096);                // 2 MB   [256][4096] bf16
  float*    den_p  = (float*)(ws + 2229248);               // 512 KB [8][4][4096]
  __hip_bfloat16* num_p = (__hip_bfloat16*)(ws + 2753536); // 16.75 MB [8][4096][256]
  uint32_t* bmask  = (uint32_t*)(ws + 19530752);           // 2 MB   [4096][128]

  hipMemsetAsync(ws, 0, 64, stream);   // srmax2 init
  hipLaunchKernelGGL(k_prep, dim3(5120), dim3(256), 0, stream,
                     adj, hmat, W, aw, bmask, gT, slT2, srT2, srmax2);
  hipLaunchKernelGGL(k_attn, dim3(NN/BI, JSPLIT), dim3(512), 0, stream,
                     gT, slT2, srT2, srmax2, bmask, num_p, den_p);
  hipLaunchKernelGGL(k_comb, dim3(NN), dim3(256), 0, stream, num_p, den_p, out);
}

// Round 8
// 111.044 us; speedup vs baseline: 1.0088x; 1.0088x over previous
//
#include <hip/hip_runtime.h>
#include <hip/hip_bf16.h>
#include <stdint.h>

#define NN    4096
#define INF_  256
#define HEADS 4
#define HID   64
#define OUTC  256
#define NEG   0.2f
#define L2E   1.44269504f

#define BI     16
#define JSPLIT 8
#define NJ     (NN / JSPLIT)

typedef short bf16x8 __attribute__((ext_vector_type(8)));
typedef float f32x4  __attribute__((ext_vector_type(4)));

// ---- float <-> order-preserving uint encoding (for atomicMax on f32) ----
__device__ __forceinline__ uint32_t ford(float x){
  uint32_t u = __float_as_uint(x);
  return (u & 0x80000000u) ? ~u : (u | 0x80000000u);
}
__device__ __forceinline__ float funord(uint32_t e){
  uint32_t u = (e & 0x80000000u) ? (e & 0x7fffffffu) : ~e;
  return __uint_as_float(u);
}
__device__ __forceinline__ ushort bf16u(float f){
  __hip_bfloat16 b = __float2bfloat16(f);
  return *reinterpret_cast<ushort*>(&b);
}

// ---- g = h @ W^T per head-tile (f32 VALU, proven ~4-5us); emits gT (bf16,
//      [c][j] transposed), slT2/srT2 (log2e-scaled) and per-head srmax ----
__launch_bounds__(256)
__global__ void k_gemm(const float* __restrict__ hmat, const float* __restrict__ W,
                       const float* __restrict__ aw,
                       short* __restrict__ gT, float* __restrict__ slT2,
                       float* __restrict__ srT2, uint32_t* __restrict__ srmax2){
  __shared__ float hsT[64][68];   // [k][row]
  __shared__ float wsT[64][68];   // [k][col]
  __shared__ float smax_l[16];
  int t  = threadIdx.x;
  int tx = t & 15, ty = t >> 4;
  int r0 = blockIdx.x * 64;
  int cb = blockIdx.y;            // head
  int c0 = cb * 64;
  float acc[4][4] = {};

  for (int k0 = 0; k0 < INF_; k0 += 64){
    int row = t >> 2, kc = (t & 3) * 16;   // transpose-on-load (h tile)
    #pragma unroll
    for (int u = 0; u < 4; u++){
      float4 v = *(const float4*)&hmat[(r0 + row)*INF_ + k0 + kc + 4*u];
      hsT[kc + 4*u + 0][row] = v.x;
      hsT[kc + 4*u + 1][row] = v.y;
      hsT[kc + 4*u + 2][row] = v.z;
      hsT[kc + 4*u + 3][row] = v.w;
    }
    #pragma unroll
    for (int u = 0; u < 4; u++){            // W[c][k] -> wsT[k][c]
      float4 v = *(const float4*)&W[(c0 + row)*INF_ + k0 + kc + 4*u];
      wsT[kc + 4*u + 0][row] = v.x;
      wsT[kc + 4*u + 1][row] = v.y;
      wsT[kc + 4*u + 2][row] = v.z;
      wsT[kc + 4*u + 3][row] = v.w;
    }
    __syncthreads();
    #pragma unroll 8
    for (int k = 0; k < 64; k++){
      float4 hv = *(const float4*)&hsT[k][ty*4];
      float4 wv = *(const float4*)&wsT[k][tx*4];
      float ha[4] = {hv.x, hv.y, hv.z, hv.w};
      float wa[4] = {wv.x, wv.y, wv.z, wv.w};
      #pragma unroll
      for (int a_ = 0; a_ < 4; a_++)
        #pragma unroll
        for (int b_ = 0; b_ < 4; b_++)
          acc[a_][b_] = fmaf(ha[a_], wa[b_], acc[a_][b_]);
    }
    __syncthreads();
  }

  // scores (log2e-scaled)
  float alv[4], arv[4];
  #pragma unroll
  for (int j = 0; j < 4; j++){ alv[j] = aw[tx*4 + j]; arv[j] = aw[64 + tx*4 + j]; }
  float rmax = -3.4e38f;
  #pragma unroll
  for (int qi = 0; qi < 4; qi++){
    int r = r0 + ty*4 + qi;
    float slp = 0.f, srp = 0.f;
    #pragma unroll
    for (int j = 0; j < 4; j++){
      slp = fmaf(acc[qi][j], alv[j], slp);
      srp = fmaf(acc[qi][j], arv[j], srp);
    }
    #pragma unroll
    for (int m = 1; m < 16; m <<= 1){
      slp += __shfl_xor(slp, m, 64);
      srp += __shfl_xor(srp, m, 64);
    }
    if (tx == 0){
      slT2[(size_t)cb*NN + r] = slp * L2E;
      srT2[(size_t)cb*NN + r] = srp * L2E;
      rmax = fmaxf(rmax, srp * L2E);
    }
  }
  if (tx == 0) smax_l[ty] = rmax;

  // transpose acc -> gT (bf16) via LDS reuse
  float* T = (float*)hsT;                    // [c][r] stride 65
  #pragma unroll
  for (int qi = 0; qi < 4; qi++)
    #pragma unroll
    for (int j = 0; j < 4; j++)
      T[(tx*4 + j)*65 + ty*4 + qi] = acc[qi][j];
  __syncthreads();
  if (t == 0){
    float m = smax_l[0];
    #pragma unroll
    for (int i = 1; i < 16; i++) m = fmaxf(m, smax_l[i]);
    atomicMax(srmax2 + cb, ford(m));
  }
  int c = t >> 2, rb = (t & 3) * 16;
  ushort u16[16];
  #pragma unroll
  for (int v = 0; v < 16; v++) u16[v] = bf16u(T[c*65 + rb + v]);
  *(uint4*)&gT[(size_t)(c0 + c)*NN + r0 + rb]     = *(uint4*)&u16[0];
  *(uint4*)&gT[(size_t)(c0 + c)*NN + r0 + rb + 8] = *(uint4*)&u16[8];
}

// ---- fused attention: ballot-packs its own adjacency slab (read exactly once,
//      overlapped with compute), LDS-staged bm+sr, reg-dbuf B, MFMA PV ----
__launch_bounds__(256, 6)
__global__ void k_attn(const short* __restrict__ gT, const float* __restrict__ slT2,
                       const float* __restrict__ srT2, const uint32_t* __restrict__ srmax2,
                       const int* __restrict__ adj,
                       __hip_bfloat16* __restrict__ num_p, float* __restrict__ den_p){
  __shared__ uint32_t bmlds[16 * 18];   // [row][word] stride 18 -> conflict-free, 8B-aligned pairs
  __shared__ float    srs[4][512];      // [head][j - jb], log2e-scaled
  int t  = threadIdx.x;
  int h  = t >> 6, l = t & 63;
  int lr = l & 15, lg = l >> 4;
  int i0 = blockIdx.x * BI;
  int jb = blockIdx.y * NJ;
  int js = blockIdx.y;

  // ---- stage sr slice (wave h loads head h's 512 scores) ----
  {
    int jj = l * 8;
    float4 v0 = *(const float4*)&srT2[(size_t)h*NN + jb + jj];
    float4 v1 = *(const float4*)&srT2[(size_t)h*NN + jb + jj + 4];
    *(float4*)&srs[h][jj]     = v0;
    *(float4*)&srs[h][jj + 4] = v1;
  }
  // ---- ballot-pack adjacency slab 16 x 512 int32 -> 16x16 words in LDS ----
  {
    #pragma unroll 8
    for (int it = 0; it < 32; it++){
      int row   = h*4 + (it >> 3);        // wave h packs rows 4h..4h+3
      int chunk = it & 7;                 // 8 chunks of 64 j
      int v = adj[(size_t)(i0 + row)*NN + jb + chunk*64 + l];
      unsigned long long mk = __ballot(v != 0);
      if (l == 0)
        *(uint2*)&bmlds[row*18 + chunk*2] =
            make_uint2((uint32_t)mk, (uint32_t)(mk >> 32));
    }
  }

  float srmaxh = funord(srmax2[h]);
  float slv = slT2[(size_t)h*NN + i0 + lr];
  float xx  = slv + srmaxh;
  float msh = fmaxf(xx, NEG * xx);
  float d1  = slv - msh;              // z = d1 + sr
  float cc  = (NEG - 1.0f) * msh;     // neg branch: NEG*z + cc
  __syncthreads();

  f32x4 acc[4] = {};
  float denp = 0.f;
  const short* gTh = gT + (size_t)h*HID*NN;
  const short* bp[4];
  #pragma unroll
  for (int n = 0; n < 4; n++)
    bp[n] = gTh + (size_t)(n*16 + lr)*NN + jb + lg*8;

  bf16x8 Bb[2][4];
  #pragma unroll
  for (int n = 0; n < 4; n++){
    Bb[0][n] = *(const bf16x8*)(bp[n]);
    Bb[1][n] = *(const bf16x8*)(bp[n] + 32);
  }

  #pragma unroll
  for (int s = 0; s < 16; s++){
    uint32_t word = bmlds[lr*18 + s] >> (lg*8);
    float4 s0 = *(const float4*)&srs[h][s*32 + lg*8];
    float4 s1 = *(const float4*)&srs[h][s*32 + lg*8 + 4];
    float sr8[8] = {s0.x, s0.y, s0.z, s0.w, s1.x, s1.y, s1.z, s1.w};

    uint32_t pk[4];
    #pragma unroll
    for (int p = 0; p < 4; p++){
      float z0 = d1 + sr8[2*p];
      float z1 = d1 + sr8[2*p + 1];
      float w0 = __builtin_amdgcn_exp2f(fmaxf(z0, fmaf(NEG, z0, cc)));
      float w1 = __builtin_amdgcn_exp2f(fmaf(NEG, z1, cc) > z1 ? fmaf(NEG, z1, cc) : z1);
      // mask via 1-bit sign-extend (v_bfe_i32) + AND
      int m0 = (int)(word << (31 - (2*p)))     >> 31;
      int m1 = (int)(word << (31 - (2*p + 1))) >> 31;
      w0 = __uint_as_float(__float_as_uint(w0) & (uint32_t)m0);
      w1 = __uint_as_float(__float_as_uint(w1) & (uint32_t)m1);
      denp += w0;
      denp += w1;
      pk[p] = ((__float_as_uint(w0) + 0x8000u) >> 16) |
              ((__float_as_uint(w1) + 0x8000u) & 0xffff0000u);
    }
    bf16x8 A = *(bf16x8*)pk;

    __builtin_amdgcn_s_setprio(1);
    acc[0] = __builtin_amdgcn_mfma_f32_16x16x32_bf16(A, Bb[s & 1][0], acc[0], 0, 0, 0);
    acc[1] = __builtin_amdgcn_mfma_f32_16x16x32_bf16(A, Bb[s & 1][1], acc[1], 0, 0, 0);
    acc[2] = __builtin_amdgcn_mfma_f32_16x16x32_bf16(A, Bb[s & 1][2], acc[2], 0, 0, 0);
    acc[3] = __builtin_amdgcn_mfma_f32_16x16x32_bf16(A, Bb[s & 1][3], acc[3], 0, 0, 0);
    __builtin_amdgcn_s_setprio(0);

    if (s + 2 < 16){
      #pragma unroll
      for (int n = 0; n < 4; n++)
        Bb[s & 1][n] = *(const bf16x8*)(bp[n] + (s + 2)*32);
    }
  }

  // num partials (bf16): row = i0+lg*4+r, col = h*64+n*16+lr
  #pragma unroll
  for (int n = 0; n < 4; n++)
    #pragma unroll
    for (int r = 0; r < 4; r++)
      num_p[((size_t)js*NN + i0 + lg*4 + r)*OUTC + h*HID + n*16 + lr] =
          __float2bfloat16(acc[n][r]);

  denp += __shfl_xor(denp, 16, 64);
  denp += __shfl_xor(denp, 32, 64);
  if (lg == 0)
    den_p[((size_t)js*4 + h)*NN + i0 + lr] = denp;
}

// ---- combine partials: out = sum(num)/sum(den) ----
__global__ void k_comb(const __hip_bfloat16* __restrict__ num_p,
                       const float* __restrict__ den_p, float* __restrict__ out){
  int r = blockIdx.x, c = threadIdx.x;
  int h = c >> 6;
  float s = 0.f, d = 0.f;
  #pragma unroll
  for (int js = 0; js < JSPLIT; js++)
    s += __bfloat162float(num_p[((size_t)js*NN + r)*OUTC + c]);
  #pragma unroll
  for (int js = 0; js < JSPLIT; js++)
    d += den_p[((size_t)js*4 + h)*NN + r];
  out[(size_t)r*OUTC + c] = s / d;
}

extern "C" void kernel_launch(void* const* d_in, const int* in_sizes, int n_in,
                              void* d_out, int out_size, void* d_ws, size_t ws_size,
                              hipStream_t stream){
  const float* hmat = (const float*)d_in[0];
  const int*   adj  = (const int*)d_in[1];     // int32 layout confirmed in r1
  const float* W    = (const float*)d_in[2];
  const float* aw   = (const float*)d_in[3];
  float* out = (float*)d_out;
  char*  ws  = (char*)d_ws;

  // ws layout (bytes), total ~19.5 MB
  uint32_t* srmax2 = (uint32_t*)(ws);                      // 64 B
  float*    slT2   = (float*)(ws + 1024);                  // 64 KB
  float*    srT2   = (float*)(ws + 66560);                 // 64 KB
  short*    gT     = (short*)(ws + 132096);                // 2 MB   [256][4096] bf16
  float*    den_p  = (float*)(ws + 2229248);               // 512 KB [8][4][4096]
  __hip_bfloat16* num_p = (__hip_bfloat16*)(ws + 2753536); // 16.75 MB [8][4096][256]

  hipMemsetAsync(ws, 0, 64, stream);   // srmax2 init
  hipLaunchKernelGGL(k_gemm, dim3(64, 4), dim3(256), 0, stream,
                     hmat, W, aw, gT, slT2, srT2, srmax2);
  hipLaunchKernelGGL(k_attn, dim3(NN/BI, JSPLIT), dim3(256), 0, stream,
                     gT, slT2, srT2, srmax2, adj, num_p, den_p);
  hipLaunchKernelGGL(k_comb, dim3(NN), dim3(256), 0, stream, num_p, den_p, out);
}

// Round 9
// 103.902 us; speedup vs baseline: 1.0781x; 1.0687x over previous
//
#include <hip/hip_runtime.h>
#include <hip/hip_bf16.h>
#include <stdint.h>

#define NN    4096
#define INF_  256
#define HEADS 4
#define HID   64
#define OUTC  256
#define NEG   0.2f
#define L2E   1.44269504f

#define BI     16
#define JSPLIT 8
#define NJ     (NN / JSPLIT)

typedef short bf16x8 __attribute__((ext_vector_type(8)));
typedef float f32x4  __attribute__((ext_vector_type(4)));

// ---- float <-> order-preserving uint encoding (for atomicMax on f32) ----
__device__ __forceinline__ uint32_t ford(float x){
  uint32_t u = __float_as_uint(x);
  return (u & 0x80000000u) ? ~u : (u | 0x80000000u);
}
__device__ __forceinline__ float funord(uint32_t e){
  uint32_t u = (e & 0x80000000u) ? (e & 0x7fffffffu) : ~e;
  return __uint_as_float(u);
}
__device__ __forceinline__ ushort bf16u(float f){
  __hip_bfloat16 b = __float2bfloat16(f);
  return *reinterpret_cast<ushort*>(&b);
}

// ---- adjacency int32 [4096][4096] -> bitmask [4096][128] uint32 (proven r1) ----
__global__ void k_pack(const int* __restrict__ adj, uint32_t* __restrict__ bm){
  __shared__ ushort sh[256];
  int i = blockIdx.x;
  int t = threadIdx.x;
  const int* row = adj + (size_t)i*NN + t*16;
  uint32_t b = 0;
  #pragma unroll
  for (int u = 0; u < 4; u++){
    int4 v = *(const int4*)(row + u*4);
    b |= (v.x ? 1u : 0u) << (u*4 + 0);
    b |= (v.y ? 1u : 0u) << (u*4 + 1);
    b |= (v.z ? 1u : 0u) << (u*4 + 2);
    b |= (v.w ? 1u : 0u) << (u*4 + 3);
  }
  sh[t] = (ushort)b;
  __syncthreads();
  if (t < 128)
    bm[(size_t)i*128 + t] = (uint32_t)sh[2*t] | ((uint32_t)sh[2*t + 1] << 16);
}

// ---- g = h @ W^T per head-tile (f32 VALU, proven ~5us); emits gT (bf16,
//      [c][j] transposed), slT2/srT2 (log2e-scaled) and per-head srmax ----
__launch_bounds__(256)
__global__ void k_gemm(const float* __restrict__ hmat, const float* __restrict__ W,
                       const float* __restrict__ aw,
                       short* __restrict__ gT, float* __restrict__ slT2,
                       float* __restrict__ srT2, uint32_t* __restrict__ srmax2){
  __shared__ float hsT[64][68];   // [k][row]
  __shared__ float wsT[64][68];   // [k][col]
  __shared__ float smax_l[16];
  int t  = threadIdx.x;
  int tx = t & 15, ty = t >> 4;
  int r0 = blockIdx.x * 64;
  int cb = blockIdx.y;            // head
  int c0 = cb * 64;
  float acc[4][4] = {};

  for (int k0 = 0; k0 < INF_; k0 += 64){
    int row = t >> 2, kc = (t & 3) * 16;   // transpose-on-load (h tile)
    #pragma unroll
    for (int u = 0; u < 4; u++){
      float4 v = *(const float4*)&hmat[(r0 + row)*INF_ + k0 + kc + 4*u];
      hsT[kc + 4*u + 0][row] = v.x;
      hsT[kc + 4*u + 1][row] = v.y;
      hsT[kc + 4*u + 2][row] = v.z;
      hsT[kc + 4*u + 3][row] = v.w;
    }
    #pragma unroll
    for (int u = 0; u < 4; u++){            // W[c][k] -> wsT[k][c]
      float4 v = *(const float4*)&W[(c0 + row)*INF_ + k0 + kc + 4*u];
      wsT[kc + 4*u + 0][row] = v.x;
      wsT[kc + 4*u + 1][row] = v.y;
      wsT[kc + 4*u + 2][row] = v.z;
      wsT[kc + 4*u + 3][row] = v.w;
    }
    __syncthreads();
    #pragma unroll 8
    for (int k = 0; k < 64; k++){
      float4 hv = *(const float4*)&hsT[k][ty*4];
      float4 wv = *(const float4*)&wsT[k][tx*4];
      float ha[4] = {hv.x, hv.y, hv.z, hv.w};
      float wa[4] = {wv.x, wv.y, wv.z, wv.w};
      #pragma unroll
      for (int a_ = 0; a_ < 4; a_++)
        #pragma unroll
        for (int b_ = 0; b_ < 4; b_++)
          acc[a_][b_] = fmaf(ha[a_], wa[b_], acc[a_][b_]);
    }
    __syncthreads();
  }

  // scores (log2e-scaled)
  float alv[4], arv[4];
  #pragma unroll
  for (int j = 0; j < 4; j++){ alv[j] = aw[tx*4 + j]; arv[j] = aw[64 + tx*4 + j]; }
  float rmax = -3.4e38f;
  #pragma unroll
  for (int qi = 0; qi < 4; qi++){
    int r = r0 + ty*4 + qi;
    float slp = 0.f, srp = 0.f;
    #pragma unroll
    for (int j = 0; j < 4; j++){
      slp = fmaf(acc[qi][j], alv[j], slp);
      srp = fmaf(acc[qi][j], arv[j], srp);
    }
    #pragma unroll
    for (int m = 1; m < 16; m <<= 1){
      slp += __shfl_xor(slp, m, 64);
      srp += __shfl_xor(srp, m, 64);
    }
    if (tx == 0){
      slT2[(size_t)cb*NN + r] = slp * L2E;
      srT2[(size_t)cb*NN + r] = srp * L2E;
      rmax = fmaxf(rmax, srp * L2E);
    }
  }
  if (tx == 0) smax_l[ty] = rmax;

  // transpose acc -> gT (bf16) via LDS reuse
  float* T = (float*)hsT;                    // [c][r] stride 65
  #pragma unroll
  for (int qi = 0; qi < 4; qi++)
    #pragma unroll
    for (int j = 0; j < 4; j++)
      T[(tx*4 + j)*65 + ty*4 + qi] = acc[qi][j];
  __syncthreads();
  if (t == 0){
    float m = smax_l[0];
    #pragma unroll
    for (int i = 1; i < 16; i++) m = fmaxf(m, smax_l[i]);
    atomicMax(srmax2 + cb, ford(m));
  }
  int c = t >> 2, rb = (t & 3) * 16;
  ushort u16[16];
  #pragma unroll
  for (int v = 0; v < 16; v++) u16[v] = bf16u(T[c*65 + rb + v]);
  *(uint4*)&gT[(size_t)(c0 + c)*NN + r0 + rb]     = *(uint4*)&u16[0];
  *(uint4*)&gT[(size_t)(c0 + c)*NN + r0 + rb + 8] = *(uint4*)&u16[8];
}

// ---- fused masked-softmax attention: BI=16, LDS-staged bm+sr, MFMA PV ----
__launch_bounds__(256, 4)
__global__ void k_attn(const short* __restrict__ gT, const float* __restrict__ slT2,
                       const float* __restrict__ srT2, const uint32_t* __restrict__ srmax2,
                       const uint32_t* __restrict__ bm,
                       __hip_bfloat16* __restrict__ num_p, float* __restrict__ den_p){
  __shared__ uint32_t bmlds[16 * 18];   // [row][word] stride 18 -> conflict-free
  __shared__ float    srs[4][512];      // [head][j - jb], log2e-scaled
  int t  = threadIdx.x;
  int h  = t >> 6, l = t & 63;
  int lr = l & 15, lg = l >> 4;
  int i0 = blockIdx.x * BI;
  int jb = blockIdx.y * NJ;
  int js = blockIdx.y;

  // stage sr slice (wave h loads its head's 512 scores) + bitmask tile
  {
    int jj = l * 8;
    *(float4*)&srs[h][jj]     = *(const float4*)&srT2[(size_t)h*NN + jb + jj];
    *(float4*)&srs[h][jj + 4] = *(const float4*)&srT2[(size_t)h*NN + jb + jj + 4];
    int r = t >> 4, w = t & 15;
    bmlds[r*18 + w] = bm[(size_t)(i0 + r)*128 + (jb >> 5) + w];
  }

  float srmaxh = funord(srmax2[h]);
  float slv = slT2[(size_t)h*NN + i0 + lr];
  float xx  = slv + srmaxh;
  float msh = fmaxf(xx, NEG * xx);
  float d1  = slv - msh;              // z = d1 + sr
  float cc  = (NEG - 1.0f) * msh;     // neg branch: NEG*z + cc
  __syncthreads();

  f32x4 acc[4] = {};
  float denp = 0.f;
  const short* gTh = gT + (size_t)h*HID*NN;
  const short* bp0 = gTh + (size_t)lr*NN + jb + lg*8;

  #pragma unroll 4
  for (int s = 0; s < 16; s++){
    bf16x8 B0 = *(const bf16x8*)(bp0 + s*32);
    bf16x8 B1 = *(const bf16x8*)(bp0 + (size_t)16*NN + s*32);
    bf16x8 B2 = *(const bf16x8*)(bp0 + (size_t)32*NN + s*32);
    bf16x8 B3 = *(const bf16x8*)(bp0 + (size_t)48*NN + s*32);

    uint32_t word = bmlds[lr*18 + s] >> (lg*8);
    float4 s0 = *(const float4*)&srs[h][s*32 + lg*8];
    float4 s1 = *(const float4*)&srs[h][s*32 + lg*8 + 4];
    float sr8[8] = {s0.x, s0.y, s0.z, s0.w, s1.x, s1.y, s1.z, s1.w};

    uint32_t pk[4];
    #pragma unroll
    for (int p = 0; p < 4; p++){
      float z0 = d1 + sr8[2*p];
      float z1 = d1 + sr8[2*p + 1];
      float w0 = __builtin_amdgcn_exp2f(fmaxf(z0, fmaf(NEG, z0, cc)));
      float w1 = __builtin_amdgcn_exp2f(fmaxf(z1, fmaf(NEG, z1, cc)));
      int m0 = (int)(word << (31 - 2*p)) >> 31;     // bit 2p   -> all-ones/zero
      int m1 = (int)(word << (30 - 2*p)) >> 31;     // bit 2p+1
      w0 = __uint_as_float(__float_as_uint(w0) & (uint32_t)m0);
      w1 = __uint_as_float(__float_as_uint(w1) & (uint32_t)m1);
      denp += w0;
      denp += w1;
      pk[p] = ((__float_as_uint(w0) + 0x8000u) >> 16) |
              ((__float_as_uint(w1) + 0x8000u) & 0xffff0000u);
    }
    bf16x8 A = *(bf16x8*)pk;

    acc[0] = __builtin_amdgcn_mfma_f32_16x16x32_bf16(A, B0, acc[0], 0, 0, 0);
    acc[1] = __builtin_amdgcn_mfma_f32_16x16x32_bf16(A, B1, acc[1], 0, 0, 0);
    acc[2] = __builtin_amdgcn_mfma_f32_16x16x32_bf16(A, B2, acc[2], 0, 0, 0);
    acc[3] = __builtin_amdgcn_mfma_f32_16x16x32_bf16(A, B3, acc[3], 0, 0, 0);
  }

  // num partials (bf16): row = i0+lg*4+r, col = h*64+n*16+lr
  #pragma unroll
  for (int n = 0; n < 4; n++)
    #pragma unroll
    for (int r = 0; r < 4; r++)
      num_p[((size_t)js*NN + i0 + lg*4 + r)*OUTC + h*HID + n*16 + lr] =
          __float2bfloat16(acc[n][r]);

  denp += __shfl_xor(denp, 16, 64);
  denp += __shfl_xor(denp, 32, 64);
  if (lg == 0)
    den_p[((size_t)js*4 + h)*NN + i0 + lr] = denp;
}

// ---- combine partials: out = sum(num)/sum(den) ----
__global__ void k_comb(const __hip_bfloat16* __restrict__ num_p,
                       const float* __restrict__ den_p, float* __restrict__ out){
  int r = blockIdx.x, c = threadIdx.x;
  int h = c >> 6;
  float s = 0.f, d = 0.f;
  #pragma unroll
  for (int js = 0; js < JSPLIT; js++)
    s += __bfloat162float(num_p[((size_t)js*NN + r)*OUTC + c]);
  #pragma unroll
  for (int js = 0; js < JSPLIT; js++)
    d += den_p[((size_t)js*4 + h)*NN + r];
  out[(size_t)r*OUTC + c] = s / d;
}

extern "C" void kernel_launch(void* const* d_in, const int* in_sizes, int n_in,
                              void* d_out, int out_size, void* d_ws, size_t ws_size,
                              hipStream_t stream){
  const float* hmat = (const float*)d_in[0];
  const int*   adj  = (const int*)d_in[1];     // int32 layout confirmed in r1
  const float* W    = (const float*)d_in[2];
  const float* aw   = (const float*)d_in[3];
  float* out = (float*)d_out;
  char*  ws  = (char*)d_ws;

  // ws layout (bytes), total ~21.6 MB
  uint32_t* srmax2 = (uint32_t*)(ws);                      // 64 B
  float*    slT2   = (float*)(ws + 1024);                  // 64 KB
  float*    srT2   = (float*)(ws + 66560);                 // 64 KB
  short*    gT     = (short*)(ws + 132096);                // 2 MB   [256][4096] bf16
  float*    den_p  = (float*)(ws + 2229248);               // 512 KB [8][4][4096]
  __hip_bfloat16* num_p = (__hip_bfloat16*)(ws + 2753536); // 16.75 MB [8][4096][256]
  uint32_t* bmask  = (uint32_t*)(ws + 19530752);           // 2 MB   [4096][128]

  hipMemsetAsync(ws, 0, 64, stream);   // srmax2 init
  hipLaunchKernelGGL(k_pack, dim3(NN), dim3(256), 0, stream, adj, bmask);
  hipLaunchKernelGGL(k_gemm, dim3(64, 4), dim3(256), 0, stream,
                     hmat, W, aw, gT, slT2, srT2, srmax2);
  hipLaunchKernelGGL(k_attn, dim3(NN/BI, JSPLIT), dim3(256), 0, stream,
                     gT, slT2, srT2, srmax2, bmask, num_p, den_p);
  hipLaunchKernelGGL(k_comb, dim3(NN), dim3(256), 0, stream, num_p, den_p, out);
}

// Round 10
// 86.168 us; speedup vs baseline: 1.3000x; 1.2058x over previous
//
#include <hip/hip_runtime.h>
#include <hip/hip_bf16.h>
#include <stdint.h>

#define NN    4096
#define INF_  256
#define HEADS 4
#define HID   64
#define OUTC  256
#define NEG   0.2f
#define L2E   1.44269504f

#define BI     32
#define JSPLIT 8
#define NJ     (NN / JSPLIT)

typedef short bf16x8 __attribute__((ext_vector_type(8)));
typedef float f32x4  __attribute__((ext_vector_type(4)));

// ---- float <-> order-preserving uint encoding (for atomicMax on f32) ----
__device__ __forceinline__ uint32_t ford(float x){
  uint32_t u = __float_as_uint(x);
  return (u & 0x80000000u) ? ~u : (u | 0x80000000u);
}
__device__ __forceinline__ float funord(uint32_t e){
  uint32_t u = (e & 0x80000000u) ? (e & 0x7fffffffu) : ~e;
  return __uint_as_float(u);
}
__device__ __forceinline__ ushort bf16u(float f){
  __hip_bfloat16 b = __float2bfloat16(f);
  return *reinterpret_cast<ushort*>(&b);
}

// ---- adjacency int32 [4096][4096] -> bitmask [4096][128] via ballot ----
// lane l of a wave reads dword j = c*64+l (coalesced 256B); __ballot gives the
// 64-bit mask in exact j order. One row per wave, 64 chunks.
__launch_bounds__(256)
__global__ void k_pack(const int* __restrict__ adj, uint32_t* __restrict__ bm){
  int row = blockIdx.x * 4 + (threadIdx.x >> 6);
  int l   = threadIdx.x & 63;
  const int* rp = adj + (size_t)row * NN;
  #pragma unroll 8
  for (int c = 0; c < 64; c++){
    unsigned long long mk = __ballot(rp[c*64 + l] != 0);
    if (l == 0)
      *(uint2*)&bm[(size_t)row*128 + c*2] =
          make_uint2((uint32_t)mk, (uint32_t)(mk >> 32));
  }
}

// ---- g = h @ W^T per head-tile (f32 VALU, proven ~4us); emits gT (bf16,
//      [c][j] transposed), slT2/srT2 (log2e-scaled) and per-head srmax ----
__launch_bounds__(256)
__global__ void k_gemm(const float* __restrict__ hmat, const float* __restrict__ W,
                       const float* __restrict__ aw,
                       short* __restrict__ gT, float* __restrict__ slT2,
                       float* __restrict__ srT2, uint32_t* __restrict__ srmax2){
  __shared__ float hsT[64][68];   // [k][row]
  __shared__ float wsT[64][68];   // [k][col]
  __shared__ float smax_l[16];
  int t  = threadIdx.x;
  int tx = t & 15, ty = t >> 4;
  int r0 = blockIdx.x * 64;
  int cb = blockIdx.y;            // head
  int c0 = cb * 64;
  float acc[4][4] = {};

  for (int k0 = 0; k0 < INF_; k0 += 64){
    int row = t >> 2, kc = (t & 3) * 16;   // transpose-on-load (h tile)
    #pragma unroll
    for (int u = 0; u < 4; u++){
      float4 v = *(const float4*)&hmat[(r0 + row)*INF_ + k0 + kc + 4*u];
      hsT[kc + 4*u + 0][row] = v.x;
      hsT[kc + 4*u + 1][row] = v.y;
      hsT[kc + 4*u + 2][row] = v.z;
      hsT[kc + 4*u + 3][row] = v.w;
    }
    #pragma unroll
    for (int u = 0; u < 4; u++){            // W[c][k] -> wsT[k][c]
      float4 v = *(const float4*)&W[(c0 + row)*INF_ + k0 + kc + 4*u];
      wsT[kc + 4*u + 0][row] = v.x;
      wsT[kc + 4*u + 1][row] = v.y;
      wsT[kc + 4*u + 2][row] = v.z;
      wsT[kc + 4*u + 3][row] = v.w;
    }
    __syncthreads();
    #pragma unroll 8
    for (int k = 0; k < 64; k++){
      float4 hv = *(const float4*)&hsT[k][ty*4];
      float4 wv = *(const float4*)&wsT[k][tx*4];
      float ha[4] = {hv.x, hv.y, hv.z, hv.w};
      float wa[4] = {wv.x, wv.y, wv.z, wv.w};
      #pragma unroll
      for (int a_ = 0; a_ < 4; a_++)
        #pragma unroll
        for (int b_ = 0; b_ < 4; b_++)
          acc[a_][b_] = fmaf(ha[a_], wa[b_], acc[a_][b_]);
    }
    __syncthreads();
  }

  // scores (log2e-scaled)
  float alv[4], arv[4];
  #pragma unroll
  for (int j = 0; j < 4; j++){ alv[j] = aw[tx*4 + j]; arv[j] = aw[64 + tx*4 + j]; }
  float rmax = -3.4e38f;
  #pragma unroll
  for (int qi = 0; qi < 4; qi++){
    int r = r0 + ty*4 + qi;
    float slp = 0.f, srp = 0.f;
    #pragma unroll
    for (int j = 0; j < 4; j++){
      slp = fmaf(acc[qi][j], alv[j], slp);
      srp = fmaf(acc[qi][j], arv[j], srp);
    }
    #pragma unroll
    for (int m = 1; m < 16; m <<= 1){
      slp += __shfl_xor(slp, m, 64);
      srp += __shfl_xor(srp, m, 64);
    }
    if (tx == 0){
      slT2[(size_t)cb*NN + r] = slp * L2E;
      srT2[(size_t)cb*NN + r] = srp * L2E;
      rmax = fmaxf(rmax, srp * L2E);
    }
  }
  if (tx == 0) smax_l[ty] = rmax;

  // transpose acc -> gT (bf16) via LDS reuse
  float* T = (float*)hsT;                    // [c][r] stride 65
  #pragma unroll
  for (int qi = 0; qi < 4; qi++)
    #pragma unroll
    for (int j = 0; j < 4; j++)
      T[(tx*4 + j)*65 + ty*4 + qi] = acc[qi][j];
  __syncthreads();
  if (t == 0){
    float m = smax_l[0];
    #pragma unroll
    for (int i = 1; i < 16; i++) m = fmaxf(m, smax_l[i]);
    atomicMax(srmax2 + cb, ford(m));
  }
  int c = t >> 2, rb = (t & 3) * 16;
  ushort u16[16];
  #pragma unroll
  for (int v = 0; v < 16; v++) u16[v] = bf16u(T[c*65 + rb + v]);
  *(uint4*)&gT[(size_t)(c0 + c)*NN + r0 + rb]     = *(uint4*)&u16[0];
  *(uint4*)&gT[(size_t)(c0 + c)*NN + r0 + rb + 8] = *(uint4*)&u16[8];
}

// ---- fused masked-softmax attention: BI=32 m=2, LDS-staged bm+sr (prefetched
//      one step ahead), reg-dbuf B, den via ones-MFMA, sign-extend masking ----
__launch_bounds__(256, 4)
__global__ void k_attn(const short* __restrict__ gT, const float* __restrict__ slT2,
                       const float* __restrict__ srT2, const uint32_t* __restrict__ srmax2,
                       const uint32_t* __restrict__ bm,
                       __hip_bfloat16* __restrict__ num_p, float* __restrict__ den_p){
  __shared__ uint32_t bmlds[32 * 18];   // [row][word] stride 18 -> conflict-free
  __shared__ float    srs[4][512];      // [head][j - jb], log2e-scaled
  int t  = threadIdx.x;
  int h  = t >> 6, l = t & 63;
  int lr = l & 15, lg = l >> 4;
  int i0 = blockIdx.x * BI;
  int jb = blockIdx.y * NJ;
  int js = blockIdx.y;

  // stage sr slice (wave h loads its head's 512 scores) + bitmask tile
  {
    int jj = l * 8;
    *(float4*)&srs[h][jj]     = *(const float4*)&srT2[(size_t)h*NN + jb + jj];
    *(float4*)&srs[h][jj + 4] = *(const float4*)&srT2[(size_t)h*NN + jb + jj + 4];
    int r = t >> 3, wd = (t & 7) * 2;
    uint2 v = *(const uint2*)&bm[(size_t)(i0 + r)*128 + (jb >> 5) + wd];
    bmlds[r*18 + wd]     = v.x;
    bmlds[r*18 + wd + 1] = v.y;
  }

  float srmaxh = funord(srmax2[h]);
  float d1[2], cc[2];
  #pragma unroll
  for (int m = 0; m < 2; m++){
    float slv = slT2[(size_t)h*NN + i0 + m*16 + lr];
    float xx  = slv + srmaxh;
    float msh = fmaxf(xx, NEG * xx);
    d1[m] = slv - msh;              // z = d1 + sr
    cc[m] = (NEG - 1.0f) * msh;     // neg branch: NEG*z + cc
  }
  __syncthreads();

  f32x4 acc[2][4] = {};
  f32x4 dacc[2]   = {};
  bf16x8 ones;
  #pragma unroll
  for (int q = 0; q < 8; q++) ones[q] = (short)0x3F80;

  const short* gTh = gT + (size_t)h*HID*NN;
  const short* bp[4];
  #pragma unroll
  for (int n = 0; n < 4; n++)
    bp[n] = gTh + (size_t)(n*16 + lr)*NN + jb + lg*8;

  bf16x8 Bb[2][4];
  #pragma unroll
  for (int n = 0; n < 4; n++){
    Bb[0][n] = *(const bf16x8*)(bp[n]);
    Bb[1][n] = *(const bf16x8*)(bp[n] + 32);
  }

  // step-0 LDS operands
  float4 s0c = *(const float4*)&srs[h][lg*8];
  float4 s1c = *(const float4*)&srs[h][lg*8 + 4];
  uint32_t w0c = bmlds[lr*18];
  uint32_t w1c = bmlds[(16 + lr)*18];

  #pragma unroll
  for (int s = 0; s < 16; s++){
    // prefetch next step's LDS operands
    float4 s0n, s1n; uint32_t w0n = 0, w1n = 0;
    if (s < 15){
      s0n = *(const float4*)&srs[h][(s+1)*32 + lg*8];
      s1n = *(const float4*)&srs[h][(s+1)*32 + lg*8 + 4];
      w0n = bmlds[lr*18 + s + 1];
      w1n = bmlds[(16 + lr)*18 + s + 1];
    }
    float sr8[8] = {s0c.x, s0c.y, s0c.z, s0c.w, s1c.x, s1c.y, s1c.z, s1c.w};

    bf16x8 A[2];
    #pragma unroll
    for (int m = 0; m < 2; m++){
      uint32_t word = (m ? w1c : w0c) >> (lg*8);
      uint32_t pk[4];
      #pragma unroll
      for (int p = 0; p < 4; p++){
        float z0 = d1[m] + sr8[2*p];
        float z1 = d1[m] + sr8[2*p + 1];
        float v0 = __builtin_amdgcn_exp2f(fmaxf(z0, fmaf(NEG, z0, cc[m])));
        float v1 = __builtin_amdgcn_exp2f(fmaxf(z1, fmaf(NEG, z1, cc[m])));
        int m0 = (int)(word << (31 - 2*p)) >> 31;     // bit 2p   -> all-ones/zero
        int m1 = (int)(word << (30 - 2*p)) >> 31;     // bit 2p+1
        v0 = __uint_as_float(__float_as_uint(v0) & (uint32_t)m0);
        v1 = __uint_as_float(__float_as_uint(v1) & (uint32_t)m1);
        pk[p] = ((__float_as_uint(v0) + 0x8000u) >> 16) |
                ((__float_as_uint(v1) + 0x8000u) & 0xffff0000u);
      }
      A[m] = *(bf16x8*)pk;
    }

    __builtin_amdgcn_s_setprio(1);
    dacc[0] = __builtin_amdgcn_mfma_f32_16x16x32_bf16(A[0], ones, dacc[0], 0, 0, 0);
    #pragma unroll
    for (int n = 0; n < 4; n++)
      acc[0][n] = __builtin_amdgcn_mfma_f32_16x16x32_bf16(A[0], Bb[s & 1][n], acc[0][n], 0, 0, 0);
    dacc[1] = __builtin_amdgcn_mfma_f32_16x16x32_bf16(A[1], ones, dacc[1], 0, 0, 0);
    #pragma unroll
    for (int n = 0; n < 4; n++)
      acc[1][n] = __builtin_amdgcn_mfma_f32_16x16x32_bf16(A[1], Bb[s & 1][n], acc[1][n], 0, 0, 0);
    __builtin_amdgcn_s_setprio(0);

    if (s + 2 < 16){
      #pragma unroll
      for (int n = 0; n < 4; n++)
        Bb[s & 1][n] = *(const bf16x8*)(bp[n] + (s + 2)*32);
    }
    s0c = s0n; s1c = s1n; w0c = w0n; w1c = w1n;
  }

  // num partials (bf16): row = i0+m*16+lg*4+r, col = h*64+n*16+lr
  #pragma unroll
  for (int m = 0; m < 2; m++)
    #pragma unroll
    for (int n = 0; n < 4; n++)
      #pragma unroll
      for (int r = 0; r < 4; r++)
        num_p[((size_t)js*NN + i0 + m*16 + lg*4 + r)*OUTC + h*HID + n*16 + lr] =
            __float2bfloat16(acc[m][n][r]);

  // den partials from ones-MFMA: row m*16+lg*4+r value sits in dacc[m][r] (any lr)
  if (lr == 0)
    #pragma unroll
    for (int m = 0; m < 2; m++)
      #pragma unroll
      for (int r = 0; r < 4; r++)
        den_p[((size_t)js*4 + h)*NN + i0 + m*16 + lg*4 + r] = dacc[m][r];
}

// ---- combine partials: out = sum(num)/sum(den), 2 cols/thread ----
__global__ void k_comb(const __hip_bfloat16* __restrict__ num_p,
                       const float* __restrict__ den_p, float* __restrict__ out){
  int t  = threadIdx.x;
  int r  = blockIdx.x*2 + (t >> 7);
  int c2 = (t & 127) * 2;
  int h  = c2 >> 6;
  float s0 = 0.f, s1 = 0.f, d = 0.f;
  #pragma unroll
  for (int js = 0; js < JSPLIT; js++){
    uint32_t u = *(const uint32_t*)&num_p[((size_t)js*NN + r)*OUTC + c2];
    s0 += __uint_as_float(u << 16);
    s1 += __uint_as_float(u & 0xffff0000u);
  }
  #pragma unroll
  for (int js = 0; js < JSPLIT; js++)
    d += den_p[((size_t)js*4 + h)*NN + r];
  float inv = 1.0f / d;
  *(float2*)&out[(size_t)r*OUTC + c2] = make_float2(s0*inv, s1*inv);
}

extern "C" void kernel_launch(void* const* d_in, const int* in_sizes, int n_in,
                              void* d_out, int out_size, void* d_ws, size_t ws_size,
                              hipStream_t stream){
  const float* hmat = (const float*)d_in[0];
  const int*   adj  = (const int*)d_in[1];     // int32 layout confirmed in r1
  const float* W    = (const float*)d_in[2];
  const float* aw   = (const float*)d_in[3];
  float* out = (float*)d_out;
  char*  ws  = (char*)d_ws;

  // ws layout (bytes), total ~21.6 MB
  uint32_t* srmax2 = (uint32_t*)(ws);                      // 64 B
  float*    slT2   = (float*)(ws + 1024);                  // 64 KB
  float*    srT2   = (float*)(ws + 66560);                 // 64 KB
  short*    gT     = (short*)(ws + 132096);                // 2 MB   [256][4096] bf16
  float*    den_p  = (float*)(ws + 2229248);               // 512 KB [8][4][4096]
  __hip_bfloat16* num_p = (__hip_bfloat16*)(ws + 2753536); // 16.75 MB [8][4096][256]
  uint32_t* bmask  = (uint32_t*)(ws + 19530752);           // 2 MB   [4096][128]

  hipMemsetAsync(ws, 0, 64, stream);   // srmax2 init
  hipLaunchKernelGGL(k_pack, dim3(NN/4), dim3(256), 0, stream, adj, bmask);
  hipLaunchKernelGGL(k_gemm, dim3(64, 4), dim3(256), 0, stream,
                     hmat, W, aw, gT, slT2, srT2, srmax2);
  hipLaunchKernelGGL(k_attn, dim3(NN/BI, JSPLIT), dim3(256), 0, stream,
                     gT, slT2, srT2, srmax2, bmask, num_p, den_p);
  hipLaunchKernelGGL(k_comb, dim3(NN/2), dim3(256), 0, stream, num_p, den_p, out);
}

// Round 11
// 77.063 us; speedup vs baseline: 1.4536x; 1.1181x over previous
//
#include <hip/hip_runtime.h>
#include <hip/hip_bf16.h>
#include <stdint.h>

#define NN    4096
#define INF_  256
#define HEADS 4
#define HID   64
#define OUTC  256
#define NEG   0.2f
#define L2E   1.44269504f

#define BI     32
#define JSPLIT 8
#define NJ     (NN / JSPLIT)

typedef short bf16x8 __attribute__((ext_vector_type(8)));
typedef float f32x4  __attribute__((ext_vector_type(4)));

// ---- float <-> order-preserving uint encoding (for atomicMax on f32) ----
__device__ __forceinline__ uint32_t ford(float x){
  uint32_t u = __float_as_uint(x);
  return (u & 0x80000000u) ? ~u : (u | 0x80000000u);
}
__device__ __forceinline__ float funord(uint32_t e){
  uint32_t u = (e & 0x80000000u) ? (e & 0x7fffffffu) : ~e;
  return __uint_as_float(u);
}
__device__ __forceinline__ ushort bf16u(float f){
  __hip_bfloat16 b = __float2bfloat16(f);
  return *reinterpret_cast<ushort*>(&b);
}

// ---- adjacency int32 [4096][4096] -> bitmask bytes [4096][512] ----
// thread t reads 16 consecutive dwords (4 independent int4 loads, all issued
// before any compare -> MLP=4), emits one ushort (bytes 2t, 2t+1). LE byte
// order makes the uint32 view identical to the word layout k_attn expects.
// No ballot, no LDS, no barrier.
__launch_bounds__(256)
__global__ void k_pack(const int* __restrict__ adj, ushort* __restrict__ bmb){
  int row = blockIdx.x;
  int t   = threadIdx.x;
  const int* p = adj + (size_t)row*NN + t*16;
  int4 v0 = *(const int4*)(p);
  int4 v1 = *(const int4*)(p + 4);
  int4 v2 = *(const int4*)(p + 8);
  int4 v3 = *(const int4*)(p + 12);
  uint32_t b = 0;
  b |= (v0.x ? 0x0001u : 0u); b |= (v0.y ? 0x0002u : 0u);
  b |= (v0.z ? 0x0004u : 0u); b |= (v0.w ? 0x0008u : 0u);
  b |= (v1.x ? 0x0010u : 0u); b |= (v1.y ? 0x0020u : 0u);
  b |= (v1.z ? 0x0040u : 0u); b |= (v1.w ? 0x0080u : 0u);
  b |= (v2.x ? 0x0100u : 0u); b |= (v2.y ? 0x0200u : 0u);
  b |= (v2.z ? 0x0400u : 0u); b |= (v2.w ? 0x0800u : 0u);
  b |= (v3.x ? 0x1000u : 0u); b |= (v3.y ? 0x2000u : 0u);
  b |= (v3.z ? 0x4000u : 0u); b |= (v3.w ? 0x8000u : 0u);
  bmb[(size_t)row*256 + t] = (ushort)b;
}

// ---- g = h @ W^T per head-tile (f32 VALU, proven); emits gT (bf16,
//      [c][j] transposed), slT2/srT2 (log2e-scaled) and per-head srmax ----
__launch_bounds__(256)
__global__ void k_gemm(const float* __restrict__ hmat, const float* __restrict__ W,
                       const float* __restrict__ aw,
                       short* __restrict__ gT, float* __restrict__ slT2,
                       float* __restrict__ srT2, uint32_t* __restrict__ srmax2){
  __shared__ float hsT[64][68];   // [k][row]
  __shared__ float wsT[64][68];   // [k][col]
  __shared__ float smax_l[16];
  int t  = threadIdx.x;
  int tx = t & 15, ty = t >> 4;
  int r0 = blockIdx.x * 64;
  int cb = blockIdx.y;            // head
  int c0 = cb * 64;
  float acc[4][4] = {};

  for (int k0 = 0; k0 < INF_; k0 += 64){
    int row = t >> 2, kc = (t & 3) * 16;   // transpose-on-load (h tile)
    #pragma unroll
    for (int u = 0; u < 4; u++){
      float4 v = *(const float4*)&hmat[(r0 + row)*INF_ + k0 + kc + 4*u];
      hsT[kc + 4*u + 0][row] = v.x;
      hsT[kc + 4*u + 1][row] = v.y;
      hsT[kc + 4*u + 2][row] = v.z;
      hsT[kc + 4*u + 3][row] = v.w;
    }
    #pragma unroll
    for (int u = 0; u < 4; u++){            // W[c][k] -> wsT[k][c]
      float4 v = *(const float4*)&W[(c0 + row)*INF_ + k0 + kc + 4*u];
      wsT[kc + 4*u + 0][row] = v.x;
      wsT[kc + 4*u + 1][row] = v.y;
      wsT[kc + 4*u + 2][row] = v.z;
      wsT[kc + 4*u + 3][row] = v.w;
    }
    __syncthreads();
    #pragma unroll 8
    for (int k = 0; k < 64; k++){
      float4 hv = *(const float4*)&hsT[k][ty*4];
      float4 wv = *(const float4*)&wsT[k][tx*4];
      float ha[4] = {hv.x, hv.y, hv.z, hv.w};
      float wa[4] = {wv.x, wv.y, wv.z, wv.w};
      #pragma unroll
      for (int a_ = 0; a_ < 4; a_++)
        #pragma unroll
        for (int b_ = 0; b_ < 4; b_++)
          acc[a_][b_] = fmaf(ha[a_], wa[b_], acc[a_][b_]);
    }
    __syncthreads();
  }

  // scores (log2e-scaled)
  float alv[4], arv[4];
  #pragma unroll
  for (int j = 0; j < 4; j++){ alv[j] = aw[tx*4 + j]; arv[j] = aw[64 + tx*4 + j]; }
  float rmax = -3.4e38f;
  #pragma unroll
  for (int qi = 0; qi < 4; qi++){
    int r = r0 + ty*4 + qi;
    float slp = 0.f, srp = 0.f;
    #pragma unroll
    for (int j = 0; j < 4; j++){
      slp = fmaf(acc[qi][j], alv[j], slp);
      srp = fmaf(acc[qi][j], arv[j], srp);
    }
    #pragma unroll
    for (int m = 1; m < 16; m <<= 1){
      slp += __shfl_xor(slp, m, 64);
      srp += __shfl_xor(srp, m, 64);
    }
    if (tx == 0){
      slT2[(size_t)cb*NN + r] = slp * L2E;
      srT2[(size_t)cb*NN + r] = srp * L2E;
      rmax = fmaxf(rmax, srp * L2E);
    }
  }
  if (tx == 0) smax_l[ty] = rmax;

  // transpose acc -> gT (bf16) via LDS reuse
  float* T = (float*)hsT;                    // [c][r] stride 65
  #pragma unroll
  for (int qi = 0; qi < 4; qi++)
    #pragma unroll
    for (int j = 0; j < 4; j++)
      T[(tx*4 + j)*65 + ty*4 + qi] = acc[qi][j];
  __syncthreads();
  if (t == 0){
    float m = smax_l[0];
    #pragma unroll
    for (int i = 1; i < 16; i++) m = fmaxf(m, smax_l[i]);
    atomicMax(srmax2 + cb, ford(m));
  }
  int c = t >> 2, rb = (t & 3) * 16;
  ushort u16[16];
  #pragma unroll
  for (int v = 0; v < 16; v++) u16[v] = bf16u(T[c*65 + rb + v]);
  *(uint4*)&gT[(size_t)(c0 + c)*NN + r0 + rb]     = *(uint4*)&u16[0];
  *(uint4*)&gT[(size_t)(c0 + c)*NN + r0 + rb + 8] = *(uint4*)&u16[8];
}

// ---- fused masked-softmax attention: BI=32 m=2, LDS-staged bm+sr (prefetched
//      one step ahead), reg-dbuf B, den via ones-MFMA, sign-extend masking ----
__launch_bounds__(256, 4)
__global__ void k_attn(const short* __restrict__ gT, const float* __restrict__ slT2,
                       const float* __restrict__ srT2, const uint32_t* __restrict__ srmax2,
                       const uint32_t* __restrict__ bm,
                       __hip_bfloat16* __restrict__ num_p, float* __restrict__ den_p){
  __shared__ uint32_t bmlds[32 * 18];   // [row][word] stride 18 -> conflict-free
  __shared__ float    srs[4][512];      // [head][j - jb], log2e-scaled
  int t  = threadIdx.x;
  int h  = t >> 6, l = t & 63;
  int lr = l & 15, lg = l >> 4;
  int i0 = blockIdx.x * BI;
  int jb = blockIdx.y * NJ;
  int js = blockIdx.y;

  // stage sr slice (wave h loads its head's 512 scores) + bitmask tile
  {
    int jj = l * 8;
    *(float4*)&srs[h][jj]     = *(const float4*)&srT2[(size_t)h*NN + jb + jj];
    *(float4*)&srs[h][jj + 4] = *(const float4*)&srT2[(size_t)h*NN + jb + jj + 4];
    int r = t >> 3, wd = (t & 7) * 2;
    uint2 v = *(const uint2*)&bm[(size_t)(i0 + r)*128 + (jb >> 5) + wd];
    bmlds[r*18 + wd]     = v.x;
    bmlds[r*18 + wd + 1] = v.y;
  }

  float srmaxh = funord(srmax2[h]);
  float d1[2], cc[2];
  #pragma unroll
  for (int m = 0; m < 2; m++){
    float slv = slT2[(size_t)h*NN + i0 + m*16 + lr];
    float xx  = slv + srmaxh;
    float msh = fmaxf(xx, NEG * xx);
    d1[m] = slv - msh;              // z = d1 + sr
    cc[m] = (NEG - 1.0f) * msh;     // neg branch: NEG*z + cc
  }
  __syncthreads();

  f32x4 acc[2][4] = {};
  f32x4 dacc[2]   = {};
  bf16x8 ones;
  #pragma unroll
  for (int q = 0; q < 8; q++) ones[q] = (short)0x3F80;

  const short* gTh = gT + (size_t)h*HID*NN;
  const short* bp[4];
  #pragma unroll
  for (int n = 0; n < 4; n++)
    bp[n] = gTh + (size_t)(n*16 + lr)*NN + jb + lg*8;

  bf16x8 Bb[2][4];
  #pragma unroll
  for (int n = 0; n < 4; n++){
    Bb[0][n] = *(const bf16x8*)(bp[n]);
    Bb[1][n] = *(const bf16x8*)(bp[n] + 32);
  }

  // step-0 LDS operands
  float4 s0c = *(const float4*)&srs[h][lg*8];
  float4 s1c = *(const float4*)&srs[h][lg*8 + 4];
  uint32_t w0c = bmlds[lr*18];
  uint32_t w1c = bmlds[(16 + lr)*18];

  #pragma unroll
  for (int s = 0; s < 16; s++){
    // prefetch next step's LDS operands
    float4 s0n, s1n; uint32_t w0n = 0, w1n = 0;
    if (s < 15){
      s0n = *(const float4*)&srs[h][(s+1)*32 + lg*8];
      s1n = *(const float4*)&srs[h][(s+1)*32 + lg*8 + 4];
      w0n = bmlds[lr*18 + s + 1];
      w1n = bmlds[(16 + lr)*18 + s + 1];
    }
    float sr8[8] = {s0c.x, s0c.y, s0c.z, s0c.w, s1c.x, s1c.y, s1c.z, s1c.w};

    bf16x8 A[2];
    #pragma unroll
    for (int m = 0; m < 2; m++){
      uint32_t word = (m ? w1c : w0c) >> (lg*8);
      uint32_t pk[4];
      #pragma unroll
      for (int p = 0; p < 4; p++){
        float z0 = d1[m] + sr8[2*p];
        float z1 = d1[m] + sr8[2*p + 1];
        float v0 = __builtin_amdgcn_exp2f(fmaxf(z0, fmaf(NEG, z0, cc[m])));
        float v1 = __builtin_amdgcn_exp2f(fmaxf(z1, fmaf(NEG, z1, cc[m])));
        int m0 = (int)(word << (31 - 2*p)) >> 31;     // bit 2p   -> all-ones/zero
        int m1 = (int)(word << (30 - 2*p)) >> 31;     // bit 2p+1
        v0 = __uint_as_float(__float_as_uint(v0) & (uint32_t)m0);
        v1 = __uint_as_float(__float_as_uint(v1) & (uint32_t)m1);
        pk[p] = ((__float_as_uint(v0) + 0x8000u) >> 16) |
                ((__float_as_uint(v1) + 0x8000u) & 0xffff0000u);
      }
      A[m] = *(bf16x8*)pk;
    }

    __builtin_amdgcn_s_setprio(1);
    dacc[0] = __builtin_amdgcn_mfma_f32_16x16x32_bf16(A[0], ones, dacc[0], 0, 0, 0);
    #pragma unroll
    for (int n = 0; n < 4; n++)
      acc[0][n] = __builtin_amdgcn_mfma_f32_16x16x32_bf16(A[0], Bb[s & 1][n], acc[0][n], 0, 0, 0);
    dacc[1] = __builtin_amdgcn_mfma_f32_16x16x32_bf16(A[1], ones, dacc[1], 0, 0, 0);
    #pragma unroll
    for (int n = 0; n < 4; n++)
      acc[1][n] = __builtin_amdgcn_mfma_f32_16x16x32_bf16(A[1], Bb[s & 1][n], acc[1][n], 0, 0, 0);
    __builtin_amdgcn_s_setprio(0);

    if (s + 2 < 16){
      #pragma unroll
      for (int n = 0; n < 4; n++)
        Bb[s & 1][n] = *(const bf16x8*)(bp[n] + (s + 2)*32);
    }
    s0c = s0n; s1c = s1n; w0c = w0n; w1c = w1n;
  }

  // num partials (bf16): row = i0+m*16+lg*4+r, col = h*64+n*16+lr
  #pragma unroll
  for (int m = 0; m < 2; m++)
    #pragma unroll
    for (int n = 0; n < 4; n++)
      #pragma unroll
      for (int r = 0; r < 4; r++)
        num_p[((size_t)js*NN + i0 + m*16 + lg*4 + r)*OUTC + h*HID + n*16 + lr] =
            __float2bfloat16(acc[m][n][r]);

  // den partials from ones-MFMA: row m*16+lg*4+r value sits in dacc[m][r] (any lr)
  if (lr == 0)
    #pragma unroll
    for (int m = 0; m < 2; m++)
      #pragma unroll
      for (int r = 0; r < 4; r++)
        den_p[((size_t)js*4 + h)*NN + i0 + m*16 + lg*4 + r] = dacc[m][r];
}

// ---- combine partials: out = sum(num)/sum(den), 2 cols/thread ----
__global__ void k_comb(const __hip_bfloat16* __restrict__ num_p,
                       const float* __restrict__ den_p, float* __restrict__ out){
  int t  = threadIdx.x;
  int r  = blockIdx.x*2 + (t >> 7);
  int c2 = (t & 127) * 2;
  int h  = c2 >> 6;
  float s0 = 0.f, s1 = 0.f, d = 0.f;
  #pragma unroll
  for (int js = 0; js < JSPLIT; js++){
    uint32_t u = *(const uint32_t*)&num_p[((size_t)js*NN + r)*OUTC + c2];
    s0 += __uint_as_float(u << 16);
    s1 += __uint_as_float(u & 0xffff0000u);
  }
  #pragma unroll
  for (int js = 0; js < JSPLIT; js++)
    d += den_p[((size_t)js*4 + h)*NN + r];
  float inv = 1.0f / d;
  *(float2*)&out[(size_t)r*OUTC + c2] = make_float2(s0*inv, s1*inv);
}

extern "C" void kernel_launch(void* const* d_in, const int* in_sizes, int n_in,
                              void* d_out, int out_size, void* d_ws, size_t ws_size,
                              hipStream_t stream){
  const float* hmat = (const float*)d_in[0];
  const int*   adj  = (const int*)d_in[1];     // int32 layout confirmed in r1
  const float* W    = (const float*)d_in[2];
  const float* aw   = (const float*)d_in[3];
  float* out = (float*)d_out;
  char*  ws  = (char*)d_ws;

  // ws layout (bytes), total ~21.6 MB
  uint32_t* srmax2 = (uint32_t*)(ws);                      // 64 B
  float*    slT2   = (float*)(ws + 1024);                  // 64 KB
  float*    srT2   = (float*)(ws + 66560);                 // 64 KB
  short*    gT     = (short*)(ws + 132096);                // 2 MB   [256][4096] bf16
  float*    den_p  = (float*)(ws + 2229248);               // 512 KB [8][4][4096]
  __hip_bfloat16* num_p = (__hip_bfloat16*)(ws + 2753536); // 16.75 MB [8][4096][256]
  uint32_t* bmask  = (uint32_t*)(ws + 19530752);           // 2 MB   [4096][128] (byte-packed)

  hipMemsetAsync(ws, 0, 64, stream);   // srmax2 init
  hipLaunchKernelGGL(k_pack, dim3(NN), dim3(256), 0, stream, adj, (ushort*)bmask);
  hipLaunchKernelGGL(k_gemm, dim3(64, 4), dim3(256), 0, stream,
                     hmat, W, aw, gT, slT2, srT2, srmax2);
  hipLaunchKernelGGL(k_attn, dim3(NN/BI, JSPLIT), dim3(256), 0, stream,
                     gT, slT2, srT2, srmax2, bmask, num_p, den_p);
  hipLaunchKernelGGL(k_comb, dim3(NN/2), dim3(256), 0, stream, num_p, den_p, out);
}